// Round 22
// baseline (219.488 us; speedup 1.0000x reference)
//
#include <hip/hip_runtime.h>
#include <hip/hip_bf16.h>

#define N 8192
#define D 512

typedef __attribute__((ext_vector_type(4))) float f32x4;
typedef __attribute__((ext_vector_type(2))) long i64x2;

#define WAITVM(n) asm volatile("s_waitcnt vmcnt(" #n ")" ::: "memory")
#define WAITLGKM asm volatile("s_waitcnt lgkmcnt(0)" ::: "memory")

__device__ __forceinline__ void g2l16(const void* g, void* l) {
  __builtin_amdgcn_global_load_lds(
      (const __attribute__((address_space(1))) void*)g,
      (__attribute__((address_space(3))) void*)l, 16, 0, 0);
}

// Prep: f32 -> fp8 e4m3, k-permuted per 64-col group (16B chunk j holds
// k{8j..8j+7} | k{32+8j..32+8j+7}) so one b128 read feeds both K=32 halves
// of an MFMA pair. sq from DEQUANTIZED values (diagonal d2 exactly 0).
__global__ __launch_bounds__(128) void prep_kernel(
    const float* __restrict__ X, const float* __restrict__ Y,
    unsigned char* __restrict__ Xb, unsigned char* __restrict__ Yb,
    float* __restrict__ sqX, float* __restrict__ sqY) {
  const int b = blockIdx.x;
  const int row = b & (N - 1);
  const float* src = (b < N) ? X : Y;
  unsigned char* dst = (b < N) ? Xb : Yb;
  float* sq = (b < N) ? sqX : sqY;
  const int t = threadIdx.x;                 // 128 threads x 4 floats = 512
  float4 v = reinterpret_cast<const float4*>(src + (size_t)row * D)[t];
  unsigned p = __builtin_amdgcn_cvt_pk_fp8_f32(v.x, v.y, 0, false);
  p = __builtin_amdgcn_cvt_pk_fp8_f32(v.z, v.w, p, true);
  float f0 = __builtin_amdgcn_cvt_f32_fp8(p, 0);
  float f1 = __builtin_amdgcn_cvt_f32_fp8(p, 1);
  float f2 = __builtin_amdgcn_cvt_f32_fp8(p, 2);
  float f3 = __builtin_amdgcn_cvt_f32_fp8(p, 3);
  float s = f0 * f0 + f1 * f1 + f2 * f2 + f3 * f3;
  const int g = t >> 4;                      // 64-col group
  const int kl = (t & 15) * 4;               // k within group
  const int dest = g * 64 + ((kl & 31) >> 3) * 16 + (kl >> 5) * 8 + (kl & 7);
  *reinterpret_cast<unsigned*>(dst + (size_t)row * D + dest) = p;
  #pragma unroll
  for (int msk = 1; msk < 64; msk <<= 1) s += __shfl_xor(s, msk);
  __shared__ float red[2];
  if ((t & 63) == 0) red[t >> 6] = s;
  __syncthreads();
  if (t == 0) sq[row] = red[0] + red[1];
}

// ZERO-BARRIER single-wave blocks: 64 threads = 1 wave per block, each
// independently computing a 64x64 tile of BOTH Gram matrices. No s_barrier
// anywhere in the K-loop — write-after-read safety is instruction order +
// lgkmcnt within the wave; vmcnt stalls are per-wave and the SIMD swaps to
// another (independent) block. 16KB LDS -> 8 blocks/CU (reg-capped:
// dual acc = 128 AGPR keeps us at 2 waves/SIMD, but now stall-independent).
__global__ __launch_bounds__(64) void hsic_main(
    const unsigned char* __restrict__ Xb, const unsigned char* __restrict__ Yb,
    const float* __restrict__ sqX, const float* __restrict__ sqY,
    float* __restrict__ rowK, float* __restrict__ rowL,
    float* __restrict__ sums) {
  __shared__ __align__(16) unsigned char sXi[4096];
  __shared__ __align__(16) unsigned char sXj[4096];
  __shared__ __align__(16) unsigned char sYi[4096];
  __shared__ __align__(16) unsigned char sYj[4096];

  // 8256 64x64 triangle tiles (tj >= ti, nb=128) = 8 XCDs x 1032.
  const int bid = (blockIdx.x & 7) * 1032 + (blockIdx.x >> 3);
  // cnt(ti) = ti*(257-ti)/2
  int ti = (int)((257.0f - sqrtf(66049.0f - 8.0f * (float)bid)) * 0.5f);
  while (ti > 0 && (ti * (257 - ti)) / 2 > bid) --ti;
  while (((ti + 1) * (256 - ti)) / 2 <= bid) ++ti;
  const int tj = ti + (bid - (ti * (257 - ti)) / 2);
  const bool diag = (ti == tj);

  const int ib = ti * 64, jb = tj * 64;
  const int t = threadIdx.x;                 // 64 threads = 1 wave
  const int fr = t & 15, fq = t >> 4;

  f32x4 accK[4][4], accL[4][4];
  #pragma unroll
  for (int m = 0; m < 4; ++m)
    #pragma unroll
    for (int n = 0; n < 4; ++n) { accK[m][n] = (f32x4)0.f; accL[m][n] = (f32x4)0.f; }

  const unsigned char* s0 = Xb + (size_t)ib * D;
  const unsigned char* s1 = Xb + (size_t)jb * D;
  const unsigned char* s2 = Yb + (size_t)ib * D;
  const unsigned char* s3 = Yb + (size_t)jb * D;

  // Stage: 64 threads x 16B = 1KB = 16 rows x 64B per issue; 4 issues/panel.
  // row = q*16 + t/4, chunk = t&3; source pre-swizzled: swz = ((row>>1)&3)<<4
  // = ((t>>3)&3)<<4 (q*16 leaves row bits 1-2 alone).
  const int srow = t >> 2;
  const int swcb = ((t & 3) * 16) ^ (((t >> 3) & 3) << 4);
  const int lo16 = t * 16;

  // 16 vmem issues per k-tile (4 per panel).
  auto stage = [&](int kt) {
    #pragma unroll
    for (int q = 0; q < 4; ++q) {
      const size_t goff = (size_t)(q * 16 + srow) * D + kt * 64 + swcb;
      const int lo = q * 1024 + lo16;
      g2l16(s0 + goff, sXi + lo);
      g2l16(s1 + goff, sXj + lo);
      g2l16(s2 + goff, sYi + lo);
      g2l16(s3 + goff, sYj + lo);
    }
  };

  const int fcol = (fq * 16) ^ (((fr >> 1) & 3) << 4);

  #pragma unroll 1
  for (int kt = 0; kt < 8; ++kt) {
    if (kt == 0) stage(0);
    WAITVM(0);                             // own 16 loads done (no barrier!)
    i64x2 ax[4], bx[4], ay[4], by[4];
    #pragma unroll
    for (int m = 0; m < 4; ++m) {
      const int ro = (m * 16 + fr) * 64 + fcol;
      ax[m] = *(const i64x2*)&sXi[ro];
      ay[m] = *(const i64x2*)&sYi[ro];
    }
    #pragma unroll
    for (int n = 0; n < 4; ++n) {
      const int ro = (n * 16 + fr) * 64 + fcol;
      bx[n] = *(const i64x2*)&sXj[ro];
      by[n] = *(const i64x2*)&sYj[ro];
    }
    WAITLGKM;                              // reads done -> safe to overwrite
    if (kt < 7) stage(kt + 1);             // loads fly under the MFMAs
    __builtin_amdgcn_s_setprio(1);
    #pragma unroll
    for (int m = 0; m < 4; ++m)
      #pragma unroll
      for (int n = 0; n < 4; ++n) {
        accK[m][n] = __builtin_amdgcn_mfma_f32_16x16x32_fp8_fp8(ax[m][0], bx[n][0], accK[m][n], 0, 0, 0);
        accK[m][n] = __builtin_amdgcn_mfma_f32_16x16x32_fp8_fp8(ax[m][1], bx[n][1], accK[m][n], 0, 0, 0);
        accL[m][n] = __builtin_amdgcn_mfma_f32_16x16x32_fp8_fp8(ay[m][0], by[n][0], accL[m][n], 0, 0, 0);
        accL[m][n] = __builtin_amdgcn_mfma_f32_16x16x32_fp8_fp8(ay[m][1], by[n][1], accL[m][n], 0, 0, 0);
      }
    __builtin_amdgcn_s_setprio(0);
  }

  // Epilogue: K = exp(-0.5*max(sq_i + sq_j - 2*G, 0)); off-diag tiles weight 2
  // and contribute column sums. All reductions in-wave (no LDS, no barrier).
  float sxj[4], syj[4];
  #pragma unroll
  for (int n = 0; n < 4; ++n) {
    const int j = jb + n * 16 + fr;
    sxj[n] = sqX[j];
    syj[n] = sqY[j];
  }
  float kl = 0.f;
  float ckK[4] = {0.f, 0.f, 0.f, 0.f}, ckL[4] = {0.f, 0.f, 0.f, 0.f};
  #pragma unroll
  for (int m = 0; m < 4; ++m) {
    #pragma unroll
    for (int r = 0; r < 4; ++r) {
      const int i = ib + m * 16 + fq * 4 + r;
      const float sxi = sqX[i], syi = sqY[i];
      float rk = 0.f, rl = 0.f;
      #pragma unroll
      for (int n = 0; n < 4; ++n) {
        float dK = fmaxf(sxi + sxj[n] - 2.f * accK[m][n][r], 0.f);
        float Kv = __expf(-0.5f * dK);
        float dL = fmaxf(syi + syj[n] - 2.f * accL[m][n][r], 0.f);
        float Lv = __expf(-0.5f * dL);
        kl += Kv * Lv;
        rk += Kv; rl += Lv;
        ckK[n] += Kv; ckL[n] += Lv;
      }
      #pragma unroll
      for (int msk = 1; msk < 16; msk <<= 1) {
        rk += __shfl_xor(rk, msk);
        rl += __shfl_xor(rl, msk);
      }
      if (fr == 0) {
        atomicAdd(&rowK[i], rk);
        atomicAdd(&rowL[i], rl);
      }
    }
  }
  if (!diag) {
    #pragma unroll
    for (int n = 0; n < 4; ++n) {
      float a2 = ckK[n], b2 = ckL[n];
      a2 += __shfl_xor(a2, 16); a2 += __shfl_xor(a2, 32);
      b2 += __shfl_xor(b2, 16); b2 += __shfl_xor(b2, 32);
      if (fq == 0) {
        const int j = jb + n * 16 + fr;
        atomicAdd(&rowK[j], a2);
        atomicAdd(&rowL[j], b2);
      }
    }
    kl *= 2.f;
  }
  #pragma unroll
  for (int msk = 1; msk < 64; msk <<= 1) kl += __shfl_xor(kl, msk);
  if (t == 0) atomicAdd(sums, kl);
}

__global__ __launch_bounds__(256) void finalize_kernel(
    const float* __restrict__ rowK, const float* __restrict__ rowL,
    const float* __restrict__ sums, float* __restrict__ out) {
  const int t = threadIdx.x;
  float dp = 0.f, sk = 0.f, sl = 0.f;
  for (int i = t; i < N; i += 256) {
    float a = rowK[i], b = rowL[i];
    dp += a * b; sk += a; sl += b;
  }
  #pragma unroll
  for (int msk = 1; msk < 64; msk <<= 1) {
    dp += __shfl_xor(dp, msk);
    sk += __shfl_xor(sk, msk);
    sl += __shfl_xor(sl, msk);
  }
  __shared__ float r[3][4];
  const int wave = t >> 6, lane = t & 63;
  if (lane == 0) { r[0][wave] = dp; r[1][wave] = sk; r[2][wave] = sl; }
  __syncthreads();
  if (t == 0) {
    float DP = r[0][0] + r[0][1] + r[0][2] + r[0][3];
    float SK = r[1][0] + r[1][1] + r[1][2] + r[1][3];
    float SL = r[2][0] + r[2][1] + r[2][2] + r[2][3];
    const float n = (float)N;
    float raw = sums[0] - (2.f / n) * DP + (SK / n) * (SL / n);
    out[0] = raw / ((n - 1.f) * (n - 1.f));
  }
}

extern "C" void kernel_launch(void* const* d_in, const int* in_sizes, int n_in,
                              void* d_out, int out_size, void* d_ws, size_t ws_size,
                              hipStream_t stream) {
  const float* X = (const float*)d_in[0];
  const float* Y = (const float*)d_in[1];
  char* ws = (char*)d_ws;
  unsigned char* Xb = (unsigned char*)ws;                    // 4 MB
  unsigned char* Yb = (unsigned char*)(ws + (size_t)N * D);  // 4 MB
  float* sqX = (float*)(ws + (size_t)2 * N * D);
  float* sqY = sqX + N;
  float* rowK = sqY + N;
  float* rowL = rowK + N;
  float* sums = rowL + N;

  (void)hipMemsetAsync(rowK, 0, (size_t)(2 * N + 16) * sizeof(float), stream);
  prep_kernel<<<2 * N, 128, 0, stream>>>(X, Y, Xb, Yb, sqX, sqY);
  const int ntiles = 128 * 129 / 2;  // 8256 64x64 triangle tiles
  hsic_main<<<ntiles, 64, 0, stream>>>(Xb, Yb, sqX, sqY, rowK, rowL, sums);
  finalize_kernel<<<1, 256, 0, stream>>>(rowK, rowL, sums, (float*)d_out);
}